// Round 19
// baseline (135.524 us; speedup 1.0000x reference)
//
#include <hip/hip_runtime.h>

#define NBINS 256
#define EPSF 1e-12f

typedef float v4f __attribute__((ext_vector_type(4)));

// R19: 2-slice chained pipeline. 256 blocks x 256 threads; block b processes
// slices 2b and 2b+1 sequentially with the R17 schedule, chaining the
// register double-buffer across slices: slice B's tile loads issue during
// slice A's write phases (va frees after PROC(A2), vb after PROC(A3)).
// Device-wide, A-writes overlap B-reads -> read/write streams mix in steady
// state; the pure-write tail halves (96 of 512 rows vs 96 of 256 in R17).
// Occupancy trade: 1 block/CU = 4 waves/CU; per-wave ILP must cover it.
// Plain stores (R10), cheap fma binning (R8), wave-private hist (R5).
__global__ __launch_bounds__(256, 2) void fused_kernel(const float* __restrict__ x,
                                                       float* __restrict__ out) {
    const int bid  = blockIdx.x;              // 0..255
    const int t    = threadIdx.x;
    const int lane = t & 63;
    const int wave = t >> 6;                  // tile COLUMN

    __shared__ unsigned int hist[4][NBINS];   // 4 KB, wave-private
    __shared__ float entA[16], entB[16];      // per-slice 4x4 entropy maps

    const float* baseA = x + ((size_t)(2 * bid) << 16) + (size_t)wave * 64;
    const float* baseB = baseA + (1 << 16);
    unsigned int* h = hist[wave];

    v4f va[16], vb[16];

#define ISSUE(buf, base, s)                                                       \
    _Pragma("unroll")                                                             \
    for (int k = 0; k < 16; ++k) {                                                \
        const int f = lane + (k << 6);        /* float4 idx 0..1023 */            \
        buf[k] = *reinterpret_cast<const v4f*>(                                   \
            (base) + (size_t)(s) * (64 * 256) + (size_t)(f >> 4) * 256 + (f & 15) * 4); \
    }

#define PROCESS(buf, s, ent)                                                      \
    {                                                                             \
        float lmin = INFINITY, lmax = -INFINITY;                                  \
        _Pragma("unroll")                                                         \
        for (int k = 0; k < 16; ++k) {                                            \
            lmin = fminf(lmin, fminf(fminf(buf[k].x, buf[k].y),                   \
                                     fminf(buf[k].z, buf[k].w)));                 \
            lmax = fmaxf(lmax, fmaxf(fmaxf(buf[k].x, buf[k].y),                   \
                                     fmaxf(buf[k].z, buf[k].w)));                 \
        }                                                                         \
        _Pragma("unroll")                                                         \
        for (int off = 32; off > 0; off >>= 1) {                                  \
            lmin = fminf(lmin, __shfl_xor(lmin, off));                            \
            lmax = fmaxf(lmax, __shfl_xor(lmax, off));                            \
        }                                                                         \
        uint4 z; z.x = z.y = z.z = z.w = 0u;  /* same-wave DS ops in-order */     \
        reinterpret_cast<uint4*>(h)[lane] = z;                                    \
        const float width = (lmax - lmin) * (1.0f / NBINS);                       \
        const float wsafe = (width > 0.0f) ? width : 1.0f;                        \
        const float inv   = 1.0f / wsafe;                                         \
        const float coff  = -lmin * inv;                                          \
        _Pragma("unroll")                                                         \
        for (int k = 0; k < 16; ++k) {                                            \
            float vals[4] = {buf[k].x, buf[k].y, buf[k].z, buf[k].w};             \
            _Pragma("unroll")                                                     \
            for (int j = 0; j < 4; ++j) {                                         \
                /* arg >= -eps; trunc==floor for >=0, tiny negatives -> 0 */      \
                int bin = (int)fmaf(vals[j], inv, coff);                          \
                bin = min(bin, 255);                                              \
                atomicAdd(&h[bin], 1u);                                           \
            }                                                                     \
        }                                                                         \
        const uint4 c    = reinterpret_cast<const uint4*>(h)[lane];               \
        const float pden = inv * (1.0f / 4096.0f);  /* 1/(4096*wsafe) */          \
        const float p0 = (float)c.x * pden + EPSF;                                \
        const float p1 = (float)c.y * pden + EPSF;                                \
        const float p2 = (float)c.z * pden + EPSF;                                \
        const float p3 = (float)c.w * pden + EPSF;                                \
        float s_ = p0 + p1 + p2 + p3;                                             \
        _Pragma("unroll")                                                         \
        for (int off = 32; off > 0; off >>= 1) s_ += __shfl_xor(s_, off);         \
        const float itot = 1.0f / s_;                                             \
        const float q0 = p0 * itot, q1 = p1 * itot;                               \
        const float q2 = p2 * itot, q3 = p3 * itot;                               \
        float e = q0 * log2f(q0) + q1 * log2f(q1)                                 \
                + q2 * log2f(q2) + q3 * log2f(q3);                                \
        _Pragma("unroll")                                                         \
        for (int off = 32; off > 0; off >>= 1) e += __shfl_xor(e, off);           \
        if (lane == 0) (ent)[((s) << 2) + wave] = -e;                             \
    }

    // ---- horizontal upsample weights (lane = x4), hoisted once ----
    const int x4 = lane;
    const int ix = (int)floorf(((x4 << 2) + 0.5f) * 0.015625f - 0.5f);
    const int x0 = max(ix, 0), x1 = min(ix + 1, 3);
    v4f wv[4];
#pragma unroll
    for (int j = 0; j < 4; ++j) {
        const float fx = ((x4 << 2) + j + 0.5f) * 0.015625f - 0.5f;
        const float wx = fx - floorf(fx);
        const float a  = 1.0f - wx, bb = wx;
        wv[j].x = ((x0 == 0) ? a : 0.0f) + ((x1 == 0) ? bb : 0.0f);
        wv[j].y = ((x0 == 1) ? a : 0.0f) + ((x1 == 1) ? bb : 0.0f);
        wv[j].z = ((x0 == 2) ? a : 0.0f) + ((x1 == 2) ? bb : 0.0f);
        wv[j].w = ((x0 == 3) ? a : 0.0f) + ((x1 == 3) ? bb : 0.0f);
    }
    v4f* outA4 = reinterpret_cast<v4f*>(out) + ((size_t)(2 * bid) << 14);
    v4f* outB4 = outA4 + (1 << 14);

    // write nrows/4 rows per wave starting at ystart (wave-strided chunks)
#define WR(ent, out4, ystart, nrows)                                              \
    _Pragma("unroll")                                                             \
    for (int i = 0; i < (nrows) / 4; ++i) {                                       \
        const int   y   = (ystart) + wave * ((nrows) / 4) + i;                    \
        const float fy  = (y + 0.5f) * 0.015625f - 0.5f;                          \
        const float fiy = floorf(fy);                                             \
        const float wy  = fy - fiy;                                               \
        const int   iy  = (int)fiy;                                               \
        const int   y0  = max(iy, 0), y1 = min(iy + 1, 3);                        \
        const v4f r0 = reinterpret_cast<const v4f*>(ent)[y0];                     \
        const v4f r1 = reinterpret_cast<const v4f*>(ent)[y1];                     \
        v4f rv = r0 * (1.0f - wy) + r1 * wy;                                      \
        v4f o;                                                                    \
        o.x = rv.x * wv[0].x + rv.y * wv[0].y + rv.z * wv[0].z + rv.w * wv[0].w;  \
        o.y = rv.x * wv[1].x + rv.y * wv[1].y + rv.z * wv[1].z + rv.w * wv[1].w;  \
        o.z = rv.x * wv[2].x + rv.y * wv[2].y + rv.z * wv[2].z + rv.w * wv[2].w;  \
        o.w = rv.x * wv[3].x + rv.y * wv[3].y + rv.z * wv[3].z + rv.w * wv[3].w;  \
        (out4)[(y << 6) + lane] = o;                                              \
    }

    // ---- chained schedule: slice A, with slice B's loads issued inside
    //      A's write phases; then slice B. 3 barriers per slice. ----
    ISSUE(va, baseA, 0)
    ISSUE(vb, baseA, 1)
    PROCESS(va, 0, entA)
    ISSUE(va, baseA, 2)
    PROCESS(vb, 1, entA)
    ISSUE(vb, baseA, 3)
    __syncthreads();            // entA rows 0,1 ready
    WR(entA, outA4, 0, 96)      // A rows 0..95
    PROCESS(va, 2, entA)
    ISSUE(va, baseB, 0)         // chain: B tile 0 in flight under A writes
    __syncthreads();            // entA row 2 ready
    WR(entA, outA4, 96, 64)     // A rows 96..159
    PROCESS(vb, 3, entA)
    ISSUE(vb, baseB, 1)         // chain: B tile 1 in flight under A writes
    __syncthreads();            // entA row 3 ready
    WR(entA, outA4, 160, 96)    // A rows 160..255 (overlaps B loads)
    PROCESS(va, 0, entB)
    ISSUE(va, baseB, 2)
    PROCESS(vb, 1, entB)
    ISSUE(vb, baseB, 3)
    __syncthreads();            // entB rows 0,1 ready
    WR(entB, outB4, 0, 96)      // B rows 0..95
    PROCESS(va, 2, entB)
    __syncthreads();            // entB row 2 ready
    WR(entB, outB4, 96, 64)     // B rows 96..159
    PROCESS(vb, 3, entB)
    __syncthreads();            // entB row 3 ready
    WR(entB, outB4, 160, 96)    // B rows 160..255 (the only pure tail)

#undef ISSUE
#undef PROCESS
#undef WR
}

extern "C" void kernel_launch(void* const* d_in, const int* in_sizes, int n_in,
                              void* d_out, int out_size, void* d_ws, size_t ws_size,
                              hipStream_t stream) {
    const float* x   = (const float*)d_in[0];
    float*       out = (float*)d_out;
    fused_kernel<<<256, 256, 0, stream>>>(x, out);
}

// Round 20
// 42.892 us; speedup vs baseline: 3.1596x; 3.1596x over previous
//
#include <hip/hip_runtime.h>

#define NBINS 256
#define EPSF 1e-12f

typedef float v4f __attribute__((ext_vector_type(4)));

// FINAL (R17 revert): fused, pipelined, 3-phase write-interleaved.
// 512 blocks x 256 threads, block = one (n,c) slice, wave w owns tile
// COLUMN w (tiles (s,w), s=0..3, register-double-buffered: 2 tile loads
// always in flight). Ent row s completes after PROCESS s. Dependency:
//   rows 0-95 need ent rows 0,1 | 96-159 need 1,2 | 160-255 need 2,3
// Write chunks {96,64,96} at the 3 barriers. Measured 43.38 us.
// Plain stores (R10: NT stores cost +2.7us), cheap fma binning (R8),
// wave-private hist (R5), fp32 recip-mul binning + IEEE-div-free entropy.
__global__ __launch_bounds__(256, 2) void fused_kernel(const float* __restrict__ x,
                                                       float* __restrict__ out) {
    const int nc   = blockIdx.x;              // 0..511
    const int t    = threadIdx.x;
    const int lane = t & 63;
    const int wave = t >> 6;                  // tile COLUMN

    __shared__ unsigned int hist[4][NBINS];   // 4 KB, wave-private
    __shared__ float ent_s[16];               // 4x4 entropy map, row-major

    const float* cbase = x + ((size_t)nc << 16) + (size_t)wave * 64;
    unsigned int* h = hist[wave];

    v4f va[16], vb[16];

#define ISSUE(buf, s)                                                             \
    _Pragma("unroll")                                                             \
    for (int k = 0; k < 16; ++k) {                                                \
        const int f = lane + (k << 6);        /* float4 idx 0..1023 */            \
        buf[k] = *reinterpret_cast<const v4f*>(                                   \
            cbase + (size_t)(s) * (64 * 256) + (size_t)(f >> 4) * 256 + (f & 15) * 4); \
    }

#define PROCESS(buf, s)                                                           \
    {                                                                             \
        float lmin = INFINITY, lmax = -INFINITY;                                  \
        _Pragma("unroll")                                                         \
        for (int k = 0; k < 16; ++k) {                                            \
            lmin = fminf(lmin, fminf(fminf(buf[k].x, buf[k].y),                   \
                                     fminf(buf[k].z, buf[k].w)));                 \
            lmax = fmaxf(lmax, fmaxf(fmaxf(buf[k].x, buf[k].y),                   \
                                     fmaxf(buf[k].z, buf[k].w)));                 \
        }                                                                         \
        _Pragma("unroll")                                                         \
        for (int off = 32; off > 0; off >>= 1) {                                  \
            lmin = fminf(lmin, __shfl_xor(lmin, off));                            \
            lmax = fmaxf(lmax, __shfl_xor(lmax, off));                            \
        }                                                                         \
        uint4 z; z.x = z.y = z.z = z.w = 0u;  /* same-wave DS ops in-order */     \
        reinterpret_cast<uint4*>(h)[lane] = z;                                    \
        const float width = (lmax - lmin) * (1.0f / NBINS);                       \
        const float wsafe = (width > 0.0f) ? width : 1.0f;                        \
        const float inv   = 1.0f / wsafe;                                         \
        const float coff  = -lmin * inv;                                          \
        _Pragma("unroll")                                                         \
        for (int k = 0; k < 16; ++k) {                                            \
            float vals[4] = {buf[k].x, buf[k].y, buf[k].z, buf[k].w};             \
            _Pragma("unroll")                                                     \
            for (int j = 0; j < 4; ++j) {                                         \
                /* arg >= -eps; trunc==floor for >=0, tiny negatives -> 0 */      \
                int bin = (int)fmaf(vals[j], inv, coff);                          \
                bin = min(bin, 255);                                              \
                atomicAdd(&h[bin], 1u);                                           \
            }                                                                     \
        }                                                                         \
        const uint4 c    = reinterpret_cast<const uint4*>(h)[lane];               \
        const float pden = inv * (1.0f / 4096.0f);  /* 1/(4096*wsafe) */          \
        const float p0 = (float)c.x * pden + EPSF;                                \
        const float p1 = (float)c.y * pden + EPSF;                                \
        const float p2 = (float)c.z * pden + EPSF;                                \
        const float p3 = (float)c.w * pden + EPSF;                                \
        float s_ = p0 + p1 + p2 + p3;                                             \
        _Pragma("unroll")                                                         \
        for (int off = 32; off > 0; off >>= 1) s_ += __shfl_xor(s_, off);         \
        const float itot = 1.0f / s_;                                             \
        const float q0 = p0 * itot, q1 = p1 * itot;                               \
        const float q2 = p2 * itot, q3 = p3 * itot;                               \
        float e = q0 * log2f(q0) + q1 * log2f(q1)                                 \
                + q2 * log2f(q2) + q3 * log2f(q3);                                \
        _Pragma("unroll")                                                         \
        for (int off = 32; off > 0; off >>= 1) e += __shfl_xor(e, off);           \
        if (lane == 0) ent_s[((s) << 2) + wave] = -e;                             \
    }

    // ---- horizontal upsample weights (lane = x4), hoisted once ----
    const int x4 = lane;
    const int ix = (int)floorf(((x4 << 2) + 0.5f) * 0.015625f - 0.5f);
    const int x0 = max(ix, 0), x1 = min(ix + 1, 3);
    v4f wv[4];
#pragma unroll
    for (int j = 0; j < 4; ++j) {
        const float fx = ((x4 << 2) + j + 0.5f) * 0.015625f - 0.5f;
        const float wx = fx - floorf(fx);
        const float a  = 1.0f - wx, bb = wx;
        wv[j].x = ((x0 == 0) ? a : 0.0f) + ((x1 == 0) ? bb : 0.0f);
        wv[j].y = ((x0 == 1) ? a : 0.0f) + ((x1 == 1) ? bb : 0.0f);
        wv[j].z = ((x0 == 2) ? a : 0.0f) + ((x1 == 2) ? bb : 0.0f);
        wv[j].w = ((x0 == 3) ? a : 0.0f) + ((x1 == 3) ? bb : 0.0f);
    }
    const v4f* er = reinterpret_cast<const v4f*>(ent_s);   // 4 rows of 4
    v4f* out4 = reinterpret_cast<v4f*>(out) + ((size_t)nc << 14);

    // write nrows/4 rows per wave starting at ystart (wave-strided chunks)
#define WR(ystart, nrows)                                                         \
    _Pragma("unroll")                                                             \
    for (int i = 0; i < (nrows) / 4; ++i) {                                       \
        const int   y   = (ystart) + wave * ((nrows) / 4) + i;                    \
        const float fy  = (y + 0.5f) * 0.015625f - 0.5f;                          \
        const float fiy = floorf(fy);                                             \
        const float wy  = fy - fiy;                                               \
        const int   iy  = (int)fiy;                                               \
        const int   y0  = max(iy, 0), y1 = min(iy + 1, 3);                        \
        const v4f r0 = er[y0];            /* uniform per wave -> broadcast */     \
        const v4f r1 = er[y1];                                                    \
        v4f rv = r0 * (1.0f - wy) + r1 * wy;                                      \
        v4f o;                                                                    \
        o.x = rv.x * wv[0].x + rv.y * wv[0].y + rv.z * wv[0].z + rv.w * wv[0].w;  \
        o.y = rv.x * wv[1].x + rv.y * wv[1].y + rv.z * wv[1].z + rv.w * wv[1].w;  \
        o.z = rv.x * wv[2].x + rv.y * wv[2].y + rv.z * wv[2].z + rv.w * wv[2].w;  \
        o.w = rv.x * wv[3].x + rv.y * wv[3].y + rv.z * wv[3].z + rv.w * wv[3].w;  \
        out4[(y << 6) + lane] = o;                                                \
    }

    // ---- pipelined schedule, {96,64,96} write chunks ----
    ISSUE(va, 0)
    ISSUE(vb, 1)
    PROCESS(va, 0)          // ent row 0
    ISSUE(va, 2)
    PROCESS(vb, 1)          // ent row 1
    ISSUE(vb, 3)
    __syncthreads();        // ent rows 0,1 complete across all waves
    WR(0, 96)               // rows 0..95    (need ent rows 0,1)
    PROCESS(va, 2)          // ent row 2
    __syncthreads();        // ent row 2 complete
    WR(96, 64)              // rows 96..159  (need ent rows 1,2)
    PROCESS(vb, 3)          // ent row 3
    __syncthreads();        // ent row 3 complete
    WR(160, 96)             // rows 160..255 (need ent rows 2,3)

#undef ISSUE
#undef PROCESS
#undef WR
}

extern "C" void kernel_launch(void* const* d_in, const int* in_sizes, int n_in,
                              void* d_out, int out_size, void* d_ws, size_t ws_size,
                              hipStream_t stream) {
    const float* x   = (const float*)d_in[0];
    float*       out = (float*)d_out;
    fused_kernel<<<512, 256, 0, stream>>>(x, out);
}